// Round 1
// baseline (783.699 us; speedup 1.0000x reference)
//
#include <hip/hip_runtime.h>
#include <hip/hip_bf16.h>

#define BB 2
#define TT 1024
#define DD 2048
#define NH 16
#define NKV 4
#define DHD 128
#define DVV 256

// LAMBDA_INIT = 0.8 - 0.6*exp(-0.3)
#define LAMBDA_INIT 0.35550906759096927f
#define ONE_MINUS_LI 0.6444909324090307f
#define QK_SCALE 0.08838834764831845f  // 128^-0.5

typedef __attribute__((ext_vector_type(8))) short bf16x8;
typedef __attribute__((ext_vector_type(4))) float f32x4;

static __device__ __forceinline__ short f2bf_s(float x) {
    __hip_bfloat16 h = __float2bfloat16(x);
    return __builtin_bit_cast(short, h);
}

// ---------------- f32 -> bf16 cast (vectorized x4) ----------------
__global__ void cast_bf16(const float* __restrict__ in, __hip_bfloat16* __restrict__ out, int n4) {
    int i = blockIdx.x * blockDim.x + threadIdx.x;
    if (i >= n4) return;
    const float4 v = reinterpret_cast<const float4*>(in)[i];
    union { ushort4 u; __hip_bfloat16 b[4]; } o;
    o.b[0] = __float2bfloat16(v.x);
    o.b[1] = __float2bfloat16(v.y);
    o.b[2] = __float2bfloat16(v.z);
    o.b[3] = __float2bfloat16(v.w);
    reinterpret_cast<ushort4*>(out)[i] = o.u;
}

// ---------------- NT GEMM: C[M][N] = A[M][K] * Bm[N][K]^T, bf16 in, f32 out ----
// 64x64 tile, BK=32, 4 waves (2x2), mfma_f32_16x16x32_bf16.
__global__ __launch_bounds__(256) void gemm_bt16(const __hip_bfloat16* __restrict__ A,
                                                 const __hip_bfloat16* __restrict__ Bm,
                                                 float* __restrict__ C,
                                                 int M, int N, int K) {
    __shared__ ushort As[64][40];   // pad 40 -> conflict-free b128 frag reads
    __shared__ ushort Bs[64][40];
    const int tid = threadIdx.x;
    const int m0 = blockIdx.y * 64, n0 = blockIdx.x * 64;
    const int lane = tid & 63, wid = tid >> 6;
    const int lo = lane & 15, hi = lane >> 4;
    const int wr = wid >> 1, wc = wid & 1;
    const int srow = tid >> 2, scol = (tid & 3) << 3;

    f32x4 zero = {0.f, 0.f, 0.f, 0.f};
    f32x4 acc[2][2];
    acc[0][0] = zero; acc[0][1] = zero; acc[1][0] = zero; acc[1][1] = zero;

    const size_t arow = (size_t)(m0 + srow) * K + scol;
    const size_t brow = (size_t)(n0 + srow) * K + scol;

    for (int k0 = 0; k0 < K; k0 += 32) {
        __syncthreads();
        *reinterpret_cast<uint4*>(&As[srow][scol]) =
            *reinterpret_cast<const uint4*>(reinterpret_cast<const ushort*>(A) + arow + k0);
        *reinterpret_cast<uint4*>(&Bs[srow][scol]) =
            *reinterpret_cast<const uint4*>(reinterpret_cast<const ushort*>(Bm) + brow + k0);
        __syncthreads();
        bf16x8 af[2], bfv[2];
#pragma unroll
        for (int mi = 0; mi < 2; ++mi)
            af[mi] = *reinterpret_cast<const bf16x8*>(&As[wr * 32 + mi * 16 + lo][hi * 8]);
#pragma unroll
        for (int ni = 0; ni < 2; ++ni)
            bfv[ni] = *reinterpret_cast<const bf16x8*>(&Bs[wc * 32 + ni * 16 + lo][hi * 8]);
#pragma unroll
        for (int mi = 0; mi < 2; ++mi)
#pragma unroll
            for (int ni = 0; ni < 2; ++ni)
                acc[mi][ni] = __builtin_amdgcn_mfma_f32_16x16x32_bf16(af[mi], bfv[ni], acc[mi][ni], 0, 0, 0);
    }
#pragma unroll
    for (int mi = 0; mi < 2; ++mi)
#pragma unroll
        for (int ni = 0; ni < 2; ++ni)
#pragma unroll
            for (int r = 0; r < 4; ++r)
                C[(size_t)(m0 + wr * 32 + mi * 16 + hi * 4 + r) * N + (n0 + wc * 32 + ni * 16 + lo)] =
                    acc[mi][ni][r];
}

// ---------------- RoPE + reorg: in [b][t][nheads*2*DHD] f32 -> out [e][b][head][t][DHD] bf16 ----
__global__ void rope_qk(const float* __restrict__ in, const int* __restrict__ pos,
                        __hip_bfloat16* __restrict__ out, int nheads) {
    int idx = blockIdx.x * blockDim.x + threadIdx.x;  // pair index
    int total = BB * TT * nheads * 2 * (DHD / 2);
    if (idx >= total) return;
    int d2 = idx & 63;
    int row = idx >> 6;              // ((b*TT + t)*nheads + head)*2 + e
    int e = row & 1;
    int tmp = row >> 1;
    int head = tmp % nheads;
    int bt = tmp / nheads;           // b*TT + t
    int t = bt & (TT - 1);
    int b = bt >> 10;

    const float* src = in + (size_t)bt * (nheads * 256) + head * 256 + e * 128 + 2 * d2;
    float x1 = src[0], x2 = src[1];
    // inv = 10000^(-2*d2/128)
    float inv = expf(-(float)d2 * (2.0f / 128.0f) * 9.210340371976184f);
    float fr = (float)pos[t] * inv;
    float sn, cs;
    sincosf(fr, &sn, &cs);
    float o1 = x1 * cs - x2 * sn;
    float o2 = x1 * sn + x2 * cs;
    __hip_bfloat16* dst = out + ((((size_t)e * BB + b) * nheads + head) * TT + t) * DHD + 2 * d2;
    dst[0] = __float2bfloat16(o1);
    dst[1] = __float2bfloat16(o2);
}

// ---------------- V transpose: [b][t][kv*256+dv] f32 -> [b][kv][dv][t] bf16 ----
__global__ void vtrans(const float* __restrict__ in, __hip_bfloat16* __restrict__ out) {
    int idx = blockIdx.x * blockDim.x + threadIdx.x;
    int total = BB * NKV * DVV * TT;
    if (idx >= total) return;
    int t = idx & (TT - 1);
    int rest = idx >> 10;
    int dv = rest & 255;
    int rest2 = rest >> 8;
    int kvi = rest2 & 3;
    int b = rest2 >> 2;
    out[idx] = __float2bfloat16(in[(size_t)(b * TT + t) * (NKV * DVV) + kvi * 256 + dv]);
}

// ---------------- flash attention, 1 wave per (qtile16, b*h, variant) ----------------
// qb: [2][B][H][T][128]  kb: [2][B][KV][T][128]  vtb: [B][KV][256][T]  Obuf: [2][B][H][T][256]
__global__ __launch_bounds__(64) void attn_fused(const __hip_bfloat16* __restrict__ qb,
                                                 const __hip_bfloat16* __restrict__ kb,
                                                 const __hip_bfloat16* __restrict__ vtb,
                                                 float* __restrict__ Obuf) {
    const int qt = blockIdx.x;
    const int bh = blockIdx.y;   // b*NH + h
    const int e = blockIdx.z;
    const int b = bh >> 4, h = bh & 15;
    const int kv = h >> 2;       // REP = 4
    const int lane = threadIdx.x;
    const int lo = lane & 15, hi = lane >> 4;

    const __hip_bfloat16* qp = qb + (((size_t)e * BB + b) * NH + h) * (size_t)TT * DHD;
    const __hip_bfloat16* kp = kb + (((size_t)e * BB + b) * NKV + kv) * (size_t)TT * DHD;
    const __hip_bfloat16* vp = vtb + ((size_t)b * NKV + kv) * (size_t)DVV * TT;

    const int q0 = qt * 16;
    bf16x8 qf[4];
#pragma unroll
    for (int kk = 0; kk < 4; ++kk)
        qf[kk] = *reinterpret_cast<const bf16x8*>(qp + (size_t)(q0 + lo) * DHD + kk * 32 + hi * 8);

    f32x4 zero = {0.f, 0.f, 0.f, 0.f};
    f32x4 O[16];
#pragma unroll
    for (int nc = 0; nc < 16; ++nc) O[nc] = zero;
    float mrow[4] = {-3e38f, -3e38f, -3e38f, -3e38f};
    float lrow[4] = {0.f, 0.f, 0.f, 0.f};

    __shared__ float Plds[16][33];  // pad 33 -> conflict-free strided reads

    const int ktmax = (q0 + 15) >> 5;
    for (int kt = 0; kt <= ktmax; ++kt) {
        const int kbase = kt * 32;
        f32x4 s[2];
        s[0] = zero; s[1] = zero;
#pragma unroll
        for (int n = 0; n < 2; ++n)
#pragma unroll
            for (int kk = 0; kk < 4; ++kk) {
                bf16x8 kf = *reinterpret_cast<const bf16x8*>(
                    kp + (size_t)(kbase + n * 16 + lo) * DHD + kk * 32 + hi * 8);
                s[n] = __builtin_amdgcn_mfma_f32_16x16x32_bf16(qf[kk], kf, s[n], 0, 0, 0);
            }
        // scale + causal mask + tile row-max
        float tm[4];
#pragma unroll
        for (int r = 0; r < 4; ++r) {
            const int row = q0 + hi * 4 + r;
#pragma unroll
            for (int n = 0; n < 2; ++n) {
                const int key = kbase + n * 16 + lo;
                float v = s[n][r] * QK_SCALE;
                s[n][r] = (key > row) ? -3e38f : v;
            }
            tm[r] = fmaxf(s[0][r], s[1][r]);
        }
#pragma unroll
        for (int mm = 1; mm < 16; mm <<= 1)
#pragma unroll
            for (int r = 0; r < 4; ++r) tm[r] = fmaxf(tm[r], __shfl_xor(tm[r], mm, 64));
        // online softmax update
        float resc[4], psum[4];
#pragma unroll
        for (int r = 0; r < 4; ++r) {
            float mn = fmaxf(mrow[r], tm[r]);
            resc[r] = expf(mrow[r] - mn);
            mrow[r] = mn;
            psum[r] = 0.f;
        }
#pragma unroll
        for (int n = 0; n < 2; ++n)
#pragma unroll
            for (int r = 0; r < 4; ++r) {
                float p = expf(s[n][r] - mrow[r]);
                s[n][r] = p;
                psum[r] += p;
            }
#pragma unroll
        for (int mm = 1; mm < 16; mm <<= 1)
#pragma unroll
            for (int r = 0; r < 4; ++r) psum[r] += __shfl_xor(psum[r], mm, 64);
#pragma unroll
        for (int r = 0; r < 4; ++r) lrow[r] = lrow[r] * resc[r] + psum[r];
#pragma unroll
        for (int nc = 0; nc < 16; ++nc)
#pragma unroll
            for (int r = 0; r < 4; ++r) O[nc][r] *= resc[r];
        // P (C-layout) -> LDS -> A-frag layout
        __syncthreads();
#pragma unroll
        for (int n = 0; n < 2; ++n)
#pragma unroll
            for (int r = 0; r < 4; ++r) Plds[hi * 4 + r][n * 16 + lo] = s[n][r];
        __syncthreads();
        bf16x8 pf;
#pragma unroll
        for (int j = 0; j < 8; ++j) pf[j] = f2bf_s(Plds[lo][hi * 8 + j]);
        // PV: O[16x256] += P[16x32] * V[32x256]
#pragma unroll
        for (int nc = 0; nc < 16; ++nc) {
            bf16x8 vf = *reinterpret_cast<const bf16x8*>(
                vp + (size_t)(nc * 16 + lo) * TT + kbase + hi * 8);
            O[nc] = __builtin_amdgcn_mfma_f32_16x16x32_bf16(pf, vf, O[nc], 0, 0, 0);
        }
    }
    float* op = Obuf + (((size_t)e * BB + b) * NH + h) * (size_t)TT * DVV;
    float invl[4];
#pragma unroll
    for (int r = 0; r < 4; ++r) invl[r] = 1.0f / lrow[r];
#pragma unroll
    for (int nc = 0; nc < 16; ++nc)
#pragma unroll
        for (int r = 0; r < 4; ++r)
            op[(size_t)(q0 + hi * 4 + r) * DVV + nc * 16 + lo] = O[nc][r] * invl[r];
}

// ---------------- combine (O1 - lam*O2) + GroupNorm(256) + scale, write bf16 ----
__global__ __launch_bounds__(256) void gn_combine(const float* __restrict__ Obuf,
                                                  const float* __restrict__ lq1, const float* __restrict__ lk1,
                                                  const float* __restrict__ lq2, const float* __restrict__ lk2,
                                                  const float* __restrict__ gw, const float* __restrict__ gb,
                                                  __hip_bfloat16* __restrict__ obf) {
    const int row = blockIdx.x;  // (b*TT + t)*NH + h
    const int h = row & 15;
    const int bt = row >> 4;
    const int b = bt >> 10, t = bt & (TT - 1);
    const int tid = threadIdx.x;
    __shared__ float2 red[256];
    __shared__ float slam;
    if (tid == 0) {
        float s1 = 0.f, s2 = 0.f;
        for (int i = 0; i < 128; ++i) {
            s1 += lq1[i] * lk1[i];
            s2 += lq2[i] * lk2[i];
        }
        slam = expf(s1) - expf(s2) + LAMBDA_INIT;
    }
    __syncthreads();
    const float lam = slam;
    const size_t base = (((size_t)b * NH + h) * TT + t) * DVV + tid;
    const float o1 = Obuf[base];
    const float o2 = Obuf[base + (size_t)BB * NH * TT * DVV];
    const float val = o1 - lam * o2;
    red[tid] = make_float2(val, val * val);
    __syncthreads();
    for (int s = 128; s > 0; s >>= 1) {
        if (tid < s) {
            red[tid].x += red[tid + s].x;
            red[tid].y += red[tid + s].y;
        }
        __syncthreads();
    }
    const float mean = red[0].x * (1.0f / 256.0f);
    const float var = red[0].y * (1.0f / 256.0f) - mean * mean;
    const float norm = (val - mean) * rsqrtf(var + 1e-5f);
    const int c = h * 256 + tid;
    const float res = (norm * gw[c] + gb[c]) * ONE_MINUS_LI;
    obf[(size_t)bt * 4096 + c] = __float2bfloat16(res);
}

// ---------------- launch ----------------
extern "C" void kernel_launch(void* const* d_in, const int* in_sizes, int n_in,
                              void* d_out, int out_size, void* d_ws, size_t ws_size,
                              hipStream_t stream) {
    const float* x = (const float*)d_in[0];
    const float* Wq = (const float*)d_in[1];
    const float* Wk = (const float*)d_in[2];
    const float* Wv = (const float*)d_in[3];
    const float* Wo = (const float*)d_in[4];
    const float* lq1 = (const float*)d_in[5];
    const float* lk1 = (const float*)d_in[6];
    const float* lq2 = (const float*)d_in[7];
    const float* lk2 = (const float*)d_in[8];
    const float* gw = (const float*)d_in[9];
    const float* gb = (const float*)d_in[10];
    const int* pos = (const int*)d_in[11];

    char* ws = (char*)d_ws;
    // workspace layout (bytes); Obuf aliases [0, 64MB) over regions dead by attention time
    const size_t oXB = 0;               // x bf16            8,388,608
    const size_t oWQ = 8388608;         // Wq bf16          16,777,216
    const size_t oWK = 25165824;        // Wk bf16           4,194,304
    const size_t oWV = 29360128;        // Wv bf16           4,194,304
    const size_t oQF = 33554432;        // Q f32            33,554,432
    const size_t oKF = 67108864;        // K f32             8,388,608
    const size_t oVF = 75497472;        // V f32             8,388,608
    const size_t oQB = 83886080;        // q rope bf16      16,777,216
    const size_t oKB = 100663296;       // k rope bf16       4,194,304
    const size_t oVT = 104857600;       // v^T bf16          4,194,304
    const size_t oON = 109051904;       // post-GN bf16     16,777,216
    const size_t oWO = 125829120;       // Wo bf16          16,777,216  (end 142,606,336)
    const size_t oATT = 0;              // Obuf f32 [2][B][H][T][256]  67,108,864 (alias)

    auto bfp = [&](size_t off) { return (__hip_bfloat16*)(ws + off); };
    auto fp = [&](size_t off) { return (float*)(ws + off); };

    int n;
    n = BB * TT * DD / 4;
    cast_bf16<<<dim3((n + 255) / 256), dim3(256), 0, stream>>>(x, bfp(oXB), n);
    n = 4096 * 2048 / 4;
    cast_bf16<<<dim3((n + 255) / 256), dim3(256), 0, stream>>>(Wq, bfp(oWQ), n);
    n = 1024 * 2048 / 4;
    cast_bf16<<<dim3((n + 255) / 256), dim3(256), 0, stream>>>(Wk, bfp(oWK), n);
    n = 1024 * 2048 / 4;
    cast_bf16<<<dim3((n + 255) / 256), dim3(256), 0, stream>>>(Wv, bfp(oWV), n);
    n = 2048 * 4096 / 4;
    cast_bf16<<<dim3((n + 255) / 256), dim3(256), 0, stream>>>(Wo, bfp(oWO), n);

    // projections
    gemm_bt16<<<dim3(4096 / 64, 2048 / 64), dim3(256), 0, stream>>>(bfp(oXB), bfp(oWQ), fp(oQF), 2048, 4096, 2048);
    gemm_bt16<<<dim3(1024 / 64, 2048 / 64), dim3(256), 0, stream>>>(bfp(oXB), bfp(oWK), fp(oKF), 2048, 1024, 2048);
    gemm_bt16<<<dim3(1024 / 64, 2048 / 64), dim3(256), 0, stream>>>(bfp(oXB), bfp(oWV), fp(oVF), 2048, 1024, 2048);

    // rope + reorg
    n = BB * TT * NH * 2 * 64;
    rope_qk<<<dim3((n + 255) / 256), dim3(256), 0, stream>>>(fp(oQF), pos, bfp(oQB), NH);
    n = BB * TT * NKV * 2 * 64;
    rope_qk<<<dim3((n + 255) / 256), dim3(256), 0, stream>>>(fp(oKF), pos, bfp(oKB), NKV);
    n = BB * NKV * DVV * TT;
    vtrans<<<dim3((n + 255) / 256), dim3(256), 0, stream>>>(fp(oVF), bfp(oVT));

    // attention (both variants)
    attn_fused<<<dim3(TT / 16, BB * NH, 2), dim3(64), 0, stream>>>(bfp(oQB), bfp(oKB), bfp(oVT), fp(oATT));

    // combine + groupnorm
    gn_combine<<<dim3(BB * TT * NH), dim3(256), 0, stream>>>(fp(oATT), lq1, lk1, lq2, lk2, gw, gb, bfp(oON));

    // output projection
    gemm_bt16<<<dim3(2048 / 64, 2048 / 64), dim3(256), 0, stream>>>(bfp(oON), bfp(oWO), (float*)d_out, 2048, 2048, 4096);
}

// Round 2
// 697.141 us; speedup vs baseline: 1.1242x; 1.1242x over previous
//
#include <hip/hip_runtime.h>
#include <hip/hip_bf16.h>

#define BB 2
#define TT 1024
#define DD 2048
#define NH 16
#define NKV 4
#define DHD 128
#define DVV 256

#define LAMBDA_INIT 0.35550906759096927f
#define ONE_MINUS_LI 0.6444909324090307f
// QK scale * log2(e), folded into Q at rope time (softmax runs in exp2 domain)
#define QSCALE (0.08838834764831845f * 1.4426950408889634f)

typedef __attribute__((ext_vector_type(8))) short bf16x8;
typedef __attribute__((ext_vector_type(4))) float f32x4;

static __device__ __forceinline__ short f2bf_s(float x) {
    __hip_bfloat16 h = __float2bfloat16(x);
    return __builtin_bit_cast(short, h);
}
static __device__ __forceinline__ float bfu2f(unsigned short u) {
    union { float f; unsigned int u32; } x;
    x.u32 = ((unsigned int)u) << 16;
    return x.f;
}

#define GLOAD_LDS16(g, l)                                                      \
    __builtin_amdgcn_global_load_lds(                                          \
        (const __attribute__((address_space(1))) unsigned int*)(g),            \
        (__attribute__((address_space(3))) unsigned int*)(l), 16, 0, 0)

// ---------------- f32 -> bf16 cast (vectorized x4) ----------------
__global__ void cast_bf16(const float* __restrict__ in, __hip_bfloat16* __restrict__ out, int n4) {
    int i = blockIdx.x * blockDim.x + threadIdx.x;
    if (i >= n4) return;
    const float4 v = reinterpret_cast<const float4*>(in)[i];
    union { ushort4 u; __hip_bfloat16 b[4]; } o;
    o.b[0] = __float2bfloat16(v.x);
    o.b[1] = __float2bfloat16(v.y);
    o.b[2] = __float2bfloat16(v.z);
    o.b[3] = __float2bfloat16(v.w);
    reinterpret_cast<ushort4*>(out)[i] = o.u;
}

// ---------------- NT GEMM, m97 structure: 128x128 tile, BK=32, global_load_lds ----
// C[M][N] = A[M][K] * Bm[N][K]^T, bf16 in, f32 out.
__global__ __launch_bounds__(256) void gemm128(const __hip_bfloat16* __restrict__ A,
                                               const __hip_bfloat16* __restrict__ Bm,
                                               float* __restrict__ C,
                                               int M, int N, int K) {
    __shared__ ushort As[128 * 32];
    __shared__ ushort Bs[128 * 32];
    const int tid = threadIdx.x;
    const int lane = tid & 63, wid = tid >> 6;
    const int lo = lane & 15, hi = lane >> 4;
    const int wr = wid >> 1, wc = wid & 1;
    const int m0 = blockIdx.y * 128, n0 = blockIdx.x * 128;

    const int srow = tid >> 2;          // 0..63 within 64-row half
    const int scol = (tid & 3) << 3;    // 0,8,16,24

    const ushort* gA = (const ushort*)A;
    const ushort* gB = (const ushort*)Bm;

    f32x4 acc[4][4];
#pragma unroll
    for (int mi = 0; mi < 4; ++mi)
#pragma unroll
        for (int ni = 0; ni < 4; ++ni) acc[mi][ni] = (f32x4){0.f, 0.f, 0.f, 0.f};

    for (int k0 = 0; k0 < K; k0 += 32) {
        __syncthreads();  // previous tile's frag reads complete before overwrite
#pragma unroll
        for (int i = 0; i < 2; ++i) {
            GLOAD_LDS16(gA + (size_t)(m0 + i * 64 + srow) * K + k0 + scol,
                        &As[(i * 256 + wid * 64) * 8]);
            GLOAD_LDS16(gB + (size_t)(n0 + i * 64 + srow) * K + k0 + scol,
                        &Bs[(i * 256 + wid * 64) * 8]);
        }
        __syncthreads();  // drains vmcnt -> staged data visible

        bf16x8 af[4], bfr[4];
#pragma unroll
        for (int mi = 0; mi < 4; ++mi)
            af[mi] = *reinterpret_cast<const bf16x8*>(&As[(wr * 64 + mi * 16 + lo) * 32 + hi * 8]);
#pragma unroll
        for (int ni = 0; ni < 4; ++ni)
            bfr[ni] = *reinterpret_cast<const bf16x8*>(&Bs[(wc * 64 + ni * 16 + lo) * 32 + hi * 8]);
        __builtin_amdgcn_s_setprio(1);
#pragma unroll
        for (int mi = 0; mi < 4; ++mi)
#pragma unroll
            for (int ni = 0; ni < 4; ++ni)
                acc[mi][ni] = __builtin_amdgcn_mfma_f32_16x16x32_bf16(af[mi], bfr[ni], acc[mi][ni], 0, 0, 0);
        __builtin_amdgcn_s_setprio(0);
    }
#pragma unroll
    for (int mi = 0; mi < 4; ++mi)
#pragma unroll
        for (int ni = 0; ni < 4; ++ni)
#pragma unroll
            for (int r = 0; r < 4; ++r)
                C[(size_t)(m0 + wr * 64 + mi * 16 + hi * 4 + r) * N + (n0 + wc * 64 + ni * 16 + lo)] =
                    acc[mi][ni][r];
}

// ---------------- RoPE + reorg (reads fused QKV f32, writes [e][b][head][t][128] bf16) ----
__global__ void rope_qk(const float* __restrict__ in, int stride, int col_base, int nheads, int hshift,
                        const int* __restrict__ pos, __hip_bfloat16* __restrict__ out, float scale) {
    int idx = blockIdx.x * blockDim.x + threadIdx.x;  // pair index
    int total = BB * TT * nheads * 2 * 64;
    if (idx >= total) return;
    int d2 = idx & 63;
    int rest = idx >> 6;
    int e = rest & 1;
    int rest2 = rest >> 1;
    int head = rest2 & (nheads - 1);
    int bt = rest2 >> hshift;
    int t = bt & (TT - 1);
    int b = bt >> 10;

    const float* src = in + (size_t)bt * stride + col_base + head * 256 + e * 128 + 2 * d2;
    float x1 = src[0], x2 = src[1];
    float inv = expf(-(float)d2 * (2.0f / 128.0f) * 9.210340371976184f);  // 10000^(-2d2/128)
    float fr = (float)pos[t] * inv;
    float sn, cs;
    sincosf(fr, &sn, &cs);
    float o1 = (x1 * cs - x2 * sn) * scale;
    float o2 = (x1 * sn + x2 * cs) * scale;
    __hip_bfloat16* dst = out + ((((size_t)e * BB + b) * nheads + head) * TT + t) * DHD + 2 * d2;
    dst[0] = __float2bfloat16(o1);
    dst[1] = __float2bfloat16(o2);
}

// ---------------- V transpose: fused QKV f32 -> [b][kv][dv][t] bf16 ----
__global__ void vtrans(const float* __restrict__ in, __hip_bfloat16* __restrict__ out) {
    int idx = blockIdx.x * blockDim.x + threadIdx.x;
    int total = BB * NKV * DVV * TT;
    if (idx >= total) return;
    int t = idx & (TT - 1);
    int rest = idx >> 10;
    int dv = rest & 255;
    int rest2 = rest >> 8;
    int kvi = rest2 & 3;
    int b = rest2 >> 2;
    out[idx] = __float2bfloat16(in[(size_t)(b * TT + t) * 6144 + 5120 + kvi * 256 + dv]);
}

// ---------------- lambda scalar ----------------
__global__ void lam_k(const float* __restrict__ lq1, const float* __restrict__ lk1,
                      const float* __restrict__ lq2, const float* __restrict__ lk2,
                      float* __restrict__ lam) {
    int l = threadIdx.x;  // 64
    float s1 = lq1[l] * lk1[l] + lq1[l + 64] * lk1[l + 64];
    float s2 = lq2[l] * lk2[l] + lq2[l + 64] * lk2[l + 64];
#pragma unroll
    for (int mm = 1; mm < 64; mm <<= 1) {
        s1 += __shfl_xor(s1, mm, 64);
        s2 += __shfl_xor(s2, mm, 64);
    }
    if (l == 0) lam[0] = expf(s1) - expf(s2) + LAMBDA_INIT;
}

// ---------------- flash attention v2: 4 waves/block, 16 q-rows/wave, KVBLK=64 ----
// qb: [2][B][H][T][128] (pre-scaled by QSCALE)  kb: [2][B][KV][T][128]
// vtb: [B][KV][256][T]  Obuf: [2][B][H][T][256] bf16
__global__ __launch_bounds__(256) void attn_fused(const __hip_bfloat16* __restrict__ qb,
                                                  const __hip_bfloat16* __restrict__ kb,
                                                  const __hip_bfloat16* __restrict__ vtb,
                                                  __hip_bfloat16* __restrict__ Obuf) {
    const int wid = threadIdx.x >> 6;
    const int lane = threadIdx.x & 63;
    const int lo = lane & 15, hi = lane >> 4;
    const int qt = blockIdx.x;
    const int bh = blockIdx.y;
    const int e = blockIdx.z;
    const int b = bh >> 4, h = bh & 15;
    const int kv = h >> 2;

    const ushort* qp = (const ushort*)qb + (((size_t)e * BB + b) * NH + h) * (size_t)TT * DHD;
    const ushort* kp = (const ushort*)kb + (((size_t)e * BB + b) * NKV + kv) * (size_t)TT * DHD;
    const ushort* vp = (const ushort*)vtb + ((size_t)b * NKV + kv) * (size_t)DVV * TT;

    const int q0 = qt * 64 + wid * 16;

    bf16x8 qf[4];
#pragma unroll
    for (int kk = 0; kk < 4; ++kk)
        qf[kk] = *reinterpret_cast<const bf16x8*>(qp + (size_t)(q0 + lo) * DHD + kk * 32 + hi * 8);

    f32x4 O[16];
#pragma unroll
    for (int nc = 0; nc < 16; ++nc) O[nc] = (f32x4){0.f, 0.f, 0.f, 0.f};
    float mrow[4] = {-3e38f, -3e38f, -3e38f, -3e38f};
    float lrow[4] = {0.f, 0.f, 0.f, 0.f};

    __shared__ float Plds[4][64][17];  // per-wave, transposed [key][qrow], stride 17 -> 2-way banks

    const int nkt = qt + 1;
    for (int kt = 0; kt < nkt; ++kt) {
        const int kbase = kt * 64;
        f32x4 s[4];
#pragma unroll
        for (int n = 0; n < 4; ++n) s[n] = (f32x4){0.f, 0.f, 0.f, 0.f};
        __builtin_amdgcn_s_setprio(1);
#pragma unroll
        for (int n = 0; n < 4; ++n)
#pragma unroll
            for (int kk = 0; kk < 4; ++kk) {
                bf16x8 kf = *reinterpret_cast<const bf16x8*>(
                    kp + (size_t)(kbase + n * 16 + lo) * DHD + kk * 32 + hi * 8);
                s[n] = __builtin_amdgcn_mfma_f32_16x16x32_bf16(qf[kk], kf, s[n], 0, 0, 0);
            }
        __builtin_amdgcn_s_setprio(0);
        if (kt == qt) {  // only the diagonal tile needs masking (uniform branch)
#pragma unroll
            for (int n = 0; n < 4; ++n) {
                const int key = kbase + n * 16 + lo;
#pragma unroll
                for (int r = 0; r < 4; ++r)
                    if (key > q0 + hi * 4 + r) s[n][r] = -3e38f;
            }
        }
        float tm[4];
#pragma unroll
        for (int r = 0; r < 4; ++r)
            tm[r] = fmaxf(fmaxf(s[0][r], s[1][r]), fmaxf(s[2][r], s[3][r]));
#pragma unroll
        for (int mm = 1; mm < 16; mm <<= 1)
#pragma unroll
            for (int r = 0; r < 4; ++r) tm[r] = fmaxf(tm[r], __shfl_xor(tm[r], mm, 64));
        // defer-max (T13): skip O/l rescale while max growth <= 11 (exp2 domain)
        int keep = (tm[0] <= mrow[0] + 11.f) && (tm[1] <= mrow[1] + 11.f) &&
                   (tm[2] <= mrow[2] + 11.f) && (tm[3] <= mrow[3] + 11.f);
        if (!__all(keep)) {
#pragma unroll
            for (int r = 0; r < 4; ++r) {
                float mn = fmaxf(mrow[r], tm[r]);
                float resc = __builtin_amdgcn_exp2f(mrow[r] - mn);
                mrow[r] = mn;
                lrow[r] *= resc;
#pragma unroll
                for (int nc = 0; nc < 16; ++nc) O[nc][r] *= resc;
            }
        }
        float rsum[4] = {0.f, 0.f, 0.f, 0.f};
#pragma unroll
        for (int n = 0; n < 4; ++n)
#pragma unroll
            for (int r = 0; r < 4; ++r) {
                float p = __builtin_amdgcn_exp2f(s[n][r] - mrow[r]);
                s[n][r] = p;
                rsum[r] += p;
            }
#pragma unroll
        for (int mm = 1; mm < 16; mm <<= 1)
#pragma unroll
            for (int r = 0; r < 4; ++r) rsum[r] += __shfl_xor(rsum[r], mm, 64);
#pragma unroll
        for (int r = 0; r < 4; ++r) lrow[r] += rsum[r];
        // P (C-layout) -> per-wave LDS (transposed) -> A-frag layout; no block barrier needed
#pragma unroll
        for (int n = 0; n < 4; ++n)
#pragma unroll
            for (int r = 0; r < 4; ++r)
                Plds[wid][n * 16 + lo][hi * 4 + r] = s[n][r];
        asm volatile("s_waitcnt lgkmcnt(0)" ::: "memory");
        bf16x8 pf[2];
#pragma unroll
        for (int ks = 0; ks < 2; ++ks)
#pragma unroll
            for (int j = 0; j < 8; ++j)
                pf[ks][j] = f2bf_s(Plds[wid][ks * 32 + hi * 8 + j][lo]);
        __builtin_amdgcn_s_setprio(1);
#pragma unroll
        for (int nc = 0; nc < 16; ++nc)
#pragma unroll
            for (int ks = 0; ks < 2; ++ks) {
                bf16x8 vf = *reinterpret_cast<const bf16x8*>(
                    vp + (size_t)(nc * 16 + lo) * TT + kbase + ks * 32 + hi * 8);
                O[nc] = __builtin_amdgcn_mfma_f32_16x16x32_bf16(pf[ks], vf, O[nc], 0, 0, 0);
            }
        __builtin_amdgcn_s_setprio(0);
    }
    ushort* op = (ushort*)Obuf + (((size_t)e * BB + b) * NH + h) * (size_t)TT * DVV;
    float invl[4];
#pragma unroll
    for (int r = 0; r < 4; ++r) invl[r] = 1.0f / lrow[r];
#pragma unroll
    for (int nc = 0; nc < 16; ++nc)
#pragma unroll
        for (int r = 0; r < 4; ++r)
            op[(size_t)(q0 + hi * 4 + r) * DVV + nc * 16 + lo] = (ushort)f2bf_s(O[nc][r] * invl[r]);
}

// ---------------- combine + GroupNorm, one wave per (b,h,t) row ----------------
__global__ __launch_bounds__(256) void gn_combine(const __hip_bfloat16* __restrict__ Obuf,
                                                  const float* __restrict__ lamp,
                                                  const float* __restrict__ gw, const float* __restrict__ gb,
                                                  __hip_bfloat16* __restrict__ obf) {
    const int wid = threadIdx.x >> 6, lane = threadIdx.x & 63;
    const int rid = blockIdx.x * 4 + wid;  // (b*NH + h)*TT + t
    const int t = rid & (TT - 1);
    const int h = (rid >> 10) & 15;
    const int b = rid >> 14;
    const float lam = lamp[0];
    const size_t E = (size_t)BB * NH * TT * DVV;
    const ushort* o1p = (const ushort*)Obuf + (size_t)rid * DVV + lane * 4;
    const ushort4 u1 = *reinterpret_cast<const ushort4*>(o1p);
    const ushort4 u2 = *reinterpret_cast<const ushort4*>(o1p + E);
    float val[4];
    val[0] = bfu2f(u1.x) - lam * bfu2f(u2.x);
    val[1] = bfu2f(u1.y) - lam * bfu2f(u2.y);
    val[2] = bfu2f(u1.z) - lam * bfu2f(u2.z);
    val[3] = bfu2f(u1.w) - lam * bfu2f(u2.w);
    float sum = val[0] + val[1] + val[2] + val[3];
    float ss = val[0] * val[0] + val[1] * val[1] + val[2] * val[2] + val[3] * val[3];
#pragma unroll
    for (int mm = 1; mm < 64; mm <<= 1) {
        sum += __shfl_xor(sum, mm, 64);
        ss += __shfl_xor(ss, mm, 64);
    }
    const float mean = sum * (1.0f / 256.0f);
    const float var = ss * (1.0f / 256.0f) - mean * mean;
    const float rs = rsqrtf(var + 1e-5f);
    const int c = h * 256 + lane * 4;
    const float4 gwv = *reinterpret_cast<const float4*>(gw + c);
    const float4 gbv = *reinterpret_cast<const float4*>(gb + c);
    union { ushort4 u; short s[4]; } o;
    o.s[0] = f2bf_s(((val[0] - mean) * rs * gwv.x + gbv.x) * ONE_MINUS_LI);
    o.s[1] = f2bf_s(((val[1] - mean) * rs * gwv.y + gbv.y) * ONE_MINUS_LI);
    o.s[2] = f2bf_s(((val[2] - mean) * rs * gwv.z + gbv.z) * ONE_MINUS_LI);
    o.s[3] = f2bf_s(((val[3] - mean) * rs * gwv.w + gbv.w) * ONE_MINUS_LI);
    const int bt = b * TT + t;
    *reinterpret_cast<ushort4*>((ushort*)obf + (size_t)bt * 4096 + c) = o.u;
}

// ---------------- launch ----------------
extern "C" void kernel_launch(void* const* d_in, const int* in_sizes, int n_in,
                              void* d_out, int out_size, void* d_ws, size_t ws_size,
                              hipStream_t stream) {
    const float* x = (const float*)d_in[0];
    const float* Wq = (const float*)d_in[1];
    const float* Wk = (const float*)d_in[2];
    const float* Wv = (const float*)d_in[3];
    const float* Wo = (const float*)d_in[4];
    const float* lq1 = (const float*)d_in[5];
    const float* lk1 = (const float*)d_in[6];
    const float* lq2 = (const float*)d_in[7];
    const float* lk2 = (const float*)d_in[8];
    const float* gw = (const float*)d_in[9];
    const float* gb = (const float*)d_in[10];
    const int* pos = (const int*)d_in[11];

    char* ws = (char*)d_ws;
    const size_t oXB = 0;                   // x bf16               8,388,608
    const size_t oWQKV = 8388608;           // [Wq;Wk;Wv] bf16     25,165,824
    const size_t oWO = 33554432;            // Wo bf16             16,777,216
    const size_t oQKVF = 50331648;          // QKV f32 [2048][6144] 50,331,648
    const size_t oOB = 50331648;            // attn out bf16 (alias, 33,554,432)
    const size_t oLAM = 83886080;           // lambda f32 (in dead QKVF tail)
    const size_t oQB = 100663296;           // q rope bf16         16,777,216
    const size_t oKB = 117440512;           // k rope bf16          4,194,304
    const size_t oVT = 121634816;           // v^T bf16             4,194,304
    const size_t oON = 125829120;           // post-GN bf16        16,777,216  (end 142,606,336)

    auto bfp = [&](size_t off) { return (__hip_bfloat16*)(ws + off); };
    auto fp = [&](size_t off) { return (float*)(ws + off); };

    int n;
    n = BB * TT * DD / 4;
    cast_bf16<<<dim3((n + 255) / 256), 256, 0, stream>>>(x, bfp(oXB), n);
    n = 4096 * 2048 / 4;
    cast_bf16<<<dim3((n + 255) / 256), 256, 0, stream>>>(Wq, bfp(oWQKV), n);
    n = 1024 * 2048 / 4;
    cast_bf16<<<dim3((n + 255) / 256), 256, 0, stream>>>(Wk, bfp(oWQKV + (size_t)4096 * 2048 * 2), n);
    cast_bf16<<<dim3((n + 255) / 256), 256, 0, stream>>>(Wv, bfp(oWQKV + (size_t)5120 * 2048 * 2), n);
    n = 2048 * 4096 / 4;
    cast_bf16<<<dim3((n + 255) / 256), 256, 0, stream>>>(Wo, bfp(oWO), n);

    // fused QKV projection: [2048][2048] x [6144][2048]^T -> [2048][6144]
    gemm128<<<dim3(6144 / 128, 2048 / 128), 256, 0, stream>>>(bfp(oXB), bfp(oWQKV), fp(oQKVF), 2048, 6144, 2048);

    // rope + reorg (Q gets QK_SCALE*log2e folded in)
    n = BB * TT * NH * 2 * 64;
    rope_qk<<<dim3((n + 255) / 256), 256, 0, stream>>>(fp(oQKVF), 6144, 0, NH, 4, pos, bfp(oQB), QSCALE);
    n = BB * TT * NKV * 2 * 64;
    rope_qk<<<dim3((n + 255) / 256), 256, 0, stream>>>(fp(oQKVF), 6144, 4096, NKV, 2, pos, bfp(oKB), 1.0f);
    n = BB * NKV * DVV * TT;
    vtrans<<<dim3((n + 255) / 256), 256, 0, stream>>>(fp(oQKVF), bfp(oVT));

    lam_k<<<dim3(1), 64, 0, stream>>>(lq1, lk1, lq2, lk2, fp(oLAM));

    // attention (both variants)
    attn_fused<<<dim3(TT / 64, BB * NH, 2), 256, 0, stream>>>(bfp(oQB), bfp(oKB), bfp(oVT), bfp(oOB));

    // combine + groupnorm
    gn_combine<<<dim3(BB * NH * TT / 4), 256, 0, stream>>>(bfp(oOB), fp(oLAM), gw, gb, bfp(oON));

    // output projection
    gemm128<<<dim3(2048 / 128, 2048 / 128), 256, 0, stream>>>(bfp(oON), bfp(oWO), (float*)d_out, 2048, 2048, 4096);
}

// Round 3
// 484.378 us; speedup vs baseline: 1.6180x; 1.4393x over previous
//
#include <hip/hip_runtime.h>
#include <hip/hip_bf16.h>

#define BB 2
#define TT 1024
#define DD 2048
#define NH 16
#define NKV 4
#define DHD 128
#define DVV 256

#define LAMBDA_INIT 0.35550906759096927f
#define ONE_MINUS_LI 0.6444909324090307f
// QK scale * log2(e), folded into Q at rope time (softmax runs in exp2 domain)
#define QSCALE (0.08838834764831845f * 1.4426950408889634f)

typedef __attribute__((ext_vector_type(8))) short bf16x8;
typedef __attribute__((ext_vector_type(4))) float f32x4;

static __device__ __forceinline__ short f2bf_s(float x) {
    __hip_bfloat16 h = __float2bfloat16(x);
    return __builtin_bit_cast(short, h);
}
static __device__ __forceinline__ float bfu2f(unsigned short u) {
    union { float f; unsigned int u32; } x;
    x.u32 = ((unsigned int)u) << 16;
    return x.f;
}

#define GLOAD_LDS16(g, l)                                                      \
    __builtin_amdgcn_global_load_lds(                                          \
        (const __attribute__((address_space(1))) unsigned int*)(g),            \
        (__attribute__((address_space(3))) unsigned int*)(l), 16, 0, 0)

// ---------------- f32 -> bf16 cast (vectorized x4) ----------------
__global__ void cast_bf16(const float* __restrict__ in, __hip_bfloat16* __restrict__ out, int n4) {
    int i = blockIdx.x * blockDim.x + threadIdx.x;
    if (i >= n4) return;
    const float4 v = reinterpret_cast<const float4*>(in)[i];
    union { ushort4 u; __hip_bfloat16 b[4]; } o;
    o.b[0] = __float2bfloat16(v.x);
    o.b[1] = __float2bfloat16(v.y);
    o.b[2] = __float2bfloat16(v.z);
    o.b[3] = __float2bfloat16(v.w);
    reinterpret_cast<ushort4*>(out)[i] = o.u;
}

// ---------------- NT GEMM, m97 structure: 128x128 tile, BK=32, global_load_lds ----
__global__ __launch_bounds__(256) void gemm128(const __hip_bfloat16* __restrict__ A,
                                               const __hip_bfloat16* __restrict__ Bm,
                                               float* __restrict__ C,
                                               int M, int N, int K) {
    __shared__ ushort As[128 * 32];
    __shared__ ushort Bs[128 * 32];
    const int tid = threadIdx.x;
    const int lane = tid & 63, wid = tid >> 6;
    const int lo = lane & 15, hi = lane >> 4;
    const int wr = wid >> 1, wc = wid & 1;
    const int m0 = blockIdx.y * 128, n0 = blockIdx.x * 128;

    const int srow = tid >> 2;
    const int scol = (tid & 3) << 3;

    const ushort* gA = (const ushort*)A;
    const ushort* gB = (const ushort*)Bm;

    f32x4 acc[4][4];
#pragma unroll
    for (int mi = 0; mi < 4; ++mi)
#pragma unroll
        for (int ni = 0; ni < 4; ++ni) acc[mi][ni] = (f32x4){0.f, 0.f, 0.f, 0.f};

    for (int k0 = 0; k0 < K; k0 += 32) {
        __syncthreads();
#pragma unroll
        for (int i = 0; i < 2; ++i) {
            GLOAD_LDS16(gA + (size_t)(m0 + i * 64 + srow) * K + k0 + scol,
                        &As[(i * 256 + wid * 64) * 8]);
            GLOAD_LDS16(gB + (size_t)(n0 + i * 64 + srow) * K + k0 + scol,
                        &Bs[(i * 256 + wid * 64) * 8]);
        }
        __syncthreads();

        bf16x8 af[4], bfr[4];
#pragma unroll
        for (int mi = 0; mi < 4; ++mi)
            af[mi] = *reinterpret_cast<const bf16x8*>(&As[(wr * 64 + mi * 16 + lo) * 32 + hi * 8]);
#pragma unroll
        for (int ni = 0; ni < 4; ++ni)
            bfr[ni] = *reinterpret_cast<const bf16x8*>(&Bs[(wc * 64 + ni * 16 + lo) * 32 + hi * 8]);
        __builtin_amdgcn_s_setprio(1);
#pragma unroll
        for (int mi = 0; mi < 4; ++mi)
#pragma unroll
            for (int ni = 0; ni < 4; ++ni)
                acc[mi][ni] = __builtin_amdgcn_mfma_f32_16x16x32_bf16(af[mi], bfr[ni], acc[mi][ni], 0, 0, 0);
        __builtin_amdgcn_s_setprio(0);
    }
#pragma unroll
    for (int mi = 0; mi < 4; ++mi)
#pragma unroll
        for (int ni = 0; ni < 4; ++ni)
#pragma unroll
            for (int r = 0; r < 4; ++r)
                C[(size_t)(m0 + wr * 64 + mi * 16 + hi * 4 + r) * N + (n0 + wc * 64 + ni * 16 + lo)] =
                    acc[mi][ni][r];
}

// ---------------- RoPE + reorg (reads fused QKV f32, writes [e][b][head][t][128] bf16) ----
__global__ void rope_qk(const float* __restrict__ in, int stride, int col_base, int nheads, int hshift,
                        const int* __restrict__ pos, __hip_bfloat16* __restrict__ out, float scale) {
    int idx = blockIdx.x * blockDim.x + threadIdx.x;
    int total = BB * TT * nheads * 2 * 64;
    if (idx >= total) return;
    int d2 = idx & 63;
    int rest = idx >> 6;
    int e = rest & 1;
    int rest2 = rest >> 1;
    int head = rest2 & (nheads - 1);
    int bt = rest2 >> hshift;
    int t = bt & (TT - 1);
    int b = bt >> 10;

    const float* src = in + (size_t)bt * stride + col_base + head * 256 + e * 128 + 2 * d2;
    float x1 = src[0], x2 = src[1];
    float inv = expf(-(float)d2 * (2.0f / 128.0f) * 9.210340371976184f);
    float fr = (float)pos[t] * inv;
    float sn, cs;
    sincosf(fr, &sn, &cs);
    float o1 = (x1 * cs - x2 * sn) * scale;
    float o2 = (x1 * sn + x2 * cs) * scale;
    __hip_bfloat16* dst = out + ((((size_t)e * BB + b) * nheads + head) * TT + t) * DHD + 2 * d2;
    dst[0] = __float2bfloat16(o1);
    dst[1] = __float2bfloat16(o2);
}

// ---------------- V transpose: fused QKV f32 -> [b][kv][dv][t] bf16 ----
__global__ void vtrans(const float* __restrict__ in, __hip_bfloat16* __restrict__ out) {
    int idx = blockIdx.x * blockDim.x + threadIdx.x;
    int total = BB * NKV * DVV * TT;
    if (idx >= total) return;
    int t = idx & (TT - 1);
    int rest = idx >> 10;
    int dv = rest & 255;
    int rest2 = rest >> 8;
    int kvi = rest2 & 3;
    int b = rest2 >> 2;
    out[idx] = __float2bfloat16(in[(size_t)(b * TT + t) * 6144 + 5120 + kvi * 256 + dv]);
}

// ---------------- lambda scalar ----------------
__global__ void lam_k(const float* __restrict__ lq1, const float* __restrict__ lk1,
                      const float* __restrict__ lq2, const float* __restrict__ lk2,
                      float* __restrict__ lam) {
    int l = threadIdx.x;  // 64
    float s1 = lq1[l] * lk1[l] + lq1[l + 64] * lk1[l + 64];
    float s2 = lq2[l] * lk2[l] + lq2[l + 64] * lk2[l + 64];
#pragma unroll
    for (int mm = 1; mm < 64; mm <<= 1) {
        s1 += __shfl_xor(s1, mm, 64);
        s2 += __shfl_xor(s2, mm, 64);
    }
    if (l == 0) lam[0] = expf(s1) - expf(s2) + LAMBDA_INIT;
}

// ---------------- flash attention v3: LDS-staged K/V, swapped QK^T, in-register softmax ----
// 4 waves/block, 16 q-rows/wave, KVBLK=64.
// qb: [2][B][H][T][128] (pre-scaled by QSCALE)  kb: [2][B][KV][T][128]
// vtb: [B][KV][256][T]  Obuf: [2][B][H][T][256] bf16
//
// K staged [64 key][128 k] bf16, 16B-chunk swizzle fK(row) = (row&3)|((row>>1)&4);
// V^T staged [256 dv][64 key] bf16, swizzle fV(dv) = dv&7. Both via pre-swizzled
// global source (global_load_lds dest must stay linear).
// QK^T computed swapped (A=K rows, B=Q) with sigma-permuted K rows so that the
// resulting P layout IS the PV A-fragment layout (zero-shuffle repack):
//   sigma(n, i) = (n>>1)*32 + (i>>2)*8 + (n&1)*4 + (i&3)
__global__ __launch_bounds__(256) void attn_fused(const __hip_bfloat16* __restrict__ qb,
                                                  const __hip_bfloat16* __restrict__ kb,
                                                  const __hip_bfloat16* __restrict__ vtb,
                                                  __hip_bfloat16* __restrict__ Obuf) {
    const int tid = threadIdx.x;
    const int wid = tid >> 6;
    const int lane = tid & 63;
    const int lo = lane & 15, hi = lane >> 4;
    const int qt = (int)gridDim.x - 1 - blockIdx.x;  // LPT: heavy blocks first
    const int bh = blockIdx.y;
    const int e = blockIdx.z;
    const int b = bh >> 4, h = bh & 15;
    const int kv = h >> 2;

    const ushort* qp = (const ushort*)qb + (((size_t)e * BB + b) * NH + h) * (size_t)TT * DHD;
    const ushort* kp = (const ushort*)kb + (((size_t)e * BB + b) * NKV + kv) * (size_t)TT * DHD;
    const ushort* vp = (const ushort*)vtb + ((size_t)b * NKV + kv) * (size_t)DVV * TT;

    const int q0 = qt * 64 + wid * 16;

    __shared__ ushort Ks[64 * 128];   // 16 KB
    __shared__ ushort Vs[256 * 64];   // 32 KB

    bf16x8 qf[4];
#pragma unroll
    for (int kk = 0; kk < 4; ++kk)
        qf[kk] = *reinterpret_cast<const bf16x8*>(qp + (size_t)(q0 + lo) * DHD + kk * 32 + hi * 8);

    f32x4 O[16];
#pragma unroll
    for (int nc = 0; nc < 16; ++nc) O[nc] = (f32x4){0.f, 0.f, 0.f, 0.f};
    float m = -3e38f, l = 0.f;   // per-lane: q-row = q0 + lo (replicated over hi)

    const int nkt = qt + 1;
    for (int kt = 0; kt < nkt; ++kt) {
        const int kbase = kt * 64;
        // ---- stage K tile (64x128) ----
#pragma unroll
        for (int p2 = 0; p2 < 4; ++p2) {
            const int idx = p2 * 256 + tid;
            const int row = idx >> 4, c = idx & 15;
            const int cp = c ^ ((row & 3) | ((row >> 1) & 4));
            GLOAD_LDS16(kp + (((size_t)(kbase + row)) << 7) + (cp << 3), &Ks[idx << 3]);
        }
        // ---- stage V^T tile (256x64) ----
#pragma unroll
        for (int p2 = 0; p2 < 8; ++p2) {
            const int idx = p2 * 256 + tid;
            const int dv = idx >> 3, c = idx & 7;
            const int cp = c ^ (dv & 7);
            GLOAD_LDS16(vp + (size_t)dv * TT + kbase + (cp << 3), &Vs[idx << 3]);
        }
        __syncthreads();  // drains vmcnt -> staged data visible

        // ---- QK^T (swapped, sigma-permuted K rows) ----
        f32x4 s[4];
#pragma unroll
        for (int n = 0; n < 4; ++n) s[n] = (f32x4){0.f, 0.f, 0.f, 0.f};
        __builtin_amdgcn_s_setprio(1);
#pragma unroll
        for (int n = 0; n < 4; ++n) {
            const int R = ((n >> 1) << 5) + ((lo >> 2) << 3) + ((n & 1) << 2) + (lo & 3);
            const int swz = ((R & 3) | ((R >> 1) & 4)) << 4;
#pragma unroll
            for (int kk = 0; kk < 4; ++kk) {
                bf16x8 kf = *reinterpret_cast<const bf16x8*>(
                    (const char*)Ks + R * 256 + ((kk * 64 + hi * 16) ^ swz));
                s[n] = __builtin_amdgcn_mfma_f32_16x16x32_bf16(kf, qf[kk], s[n], 0, 0, 0);
            }
        }
        __builtin_amdgcn_s_setprio(0);
        // lane (lo,hi) now holds S[key = kbase + (n>>1)*32 + hi*8 + (n&1)*4 + r][qrow = q0+lo]

        // ---- causal mask (only last tile reaches the diagonal) ----
        if (kt == nkt - 1) {
#pragma unroll
            for (int n = 0; n < 4; ++n) {
                const int kb0 = kbase + ((n >> 1) << 5) + ((n & 1) << 2) + hi * 8;
#pragma unroll
                for (int r = 0; r < 4; ++r)
                    if (kb0 + r > q0 + lo) s[n][r] = -3e38f;
            }
        }
        // ---- in-register row softmax: 15 fmax + 2 shfl ----
        float tm = s[0][0];
#pragma unroll
        for (int n = 0; n < 4; ++n)
#pragma unroll
            for (int r = 0; r < 4; ++r) tm = fmaxf(tm, s[n][r]);
        tm = fmaxf(tm, __shfl_xor(tm, 16, 64));
        tm = fmaxf(tm, __shfl_xor(tm, 32, 64));
        if (!__all(tm <= m + 11.f)) {   // defer-max (T13)
            const float mn = fmaxf(m, tm);
            const float resc = __builtin_amdgcn_exp2f(m - mn);
            m = mn;
            l *= resc;
            float ro[4];
#pragma unroll
            for (int r = 0; r < 4; ++r) ro[r] = __shfl(resc, hi * 4 + r, 64);
#pragma unroll
            for (int nc = 0; nc < 16; ++nc)
#pragma unroll
                for (int r = 0; r < 4; ++r) O[nc][r] *= ro[r];
        }
        float rs = 0.f;
#pragma unroll
        for (int n = 0; n < 4; ++n)
#pragma unroll
            for (int r = 0; r < 4; ++r) {
                const float p = __builtin_amdgcn_exp2f(s[n][r] - m);
                s[n][r] = p;
                rs += p;
            }
        rs += __shfl_xor(rs, 16, 64);
        rs += __shfl_xor(rs, 32, 64);
        l += rs;
        // ---- P -> A-frag: pure in-lane repack (sigma made layouts coincide) ----
        bf16x8 pf[2];
#pragma unroll
        for (int n = 0; n < 4; ++n)
#pragma unroll
            for (int r = 0; r < 4; ++r) pf[n >> 1][(n & 1) * 4 + r] = f2bf_s(s[n][r]);
        // ---- PV: O[16q x 256dv] += P[16x64] * V[64x256] ----
        __builtin_amdgcn_s_setprio(1);
#pragma unroll
        for (int nc = 0; nc < 16; ++nc) {
            const int vrow = (nc * 16 + lo) * 128;
            const int vswz = (lo & 7) << 4;
#pragma unroll
            for (int ks = 0; ks < 2; ++ks) {
                bf16x8 vf = *reinterpret_cast<const bf16x8*>(
                    (const char*)Vs + vrow + ((ks * 64 + hi * 16) ^ vswz));
                O[nc] = __builtin_amdgcn_mfma_f32_16x16x32_bf16(pf[ks], vf, O[nc], 0, 0, 0);
            }
        }
        __builtin_amdgcn_s_setprio(0);
        __syncthreads();  // all waves' LDS reads done before next stage overwrites
    }
    const float invl = 1.0f / l;
    float io[4];
#pragma unroll
    for (int r = 0; r < 4; ++r) io[r] = __shfl(invl, hi * 4 + r, 64);
    ushort* op = (ushort*)Obuf + (((size_t)e * BB + b) * NH + h) * (size_t)TT * DVV;
#pragma unroll
    for (int nc = 0; nc < 16; ++nc)
#pragma unroll
        for (int r = 0; r < 4; ++r)
            op[(size_t)(q0 + hi * 4 + r) * DVV + nc * 16 + lo] = (ushort)f2bf_s(O[nc][r] * io[r]);
}

// ---------------- combine + GroupNorm, one wave per (b,h,t) row ----------------
__global__ __launch_bounds__(256) void gn_combine(const __hip_bfloat16* __restrict__ Obuf,
                                                  const float* __restrict__ lamp,
                                                  const float* __restrict__ gw, const float* __restrict__ gb,
                                                  __hip_bfloat16* __restrict__ obf) {
    const int wid = threadIdx.x >> 6, lane = threadIdx.x & 63;
    const int rid = blockIdx.x * 4 + wid;  // (b*NH + h)*TT + t
    const int t = rid & (TT - 1);
    const int h = (rid >> 10) & 15;
    const int b = rid >> 14;
    const float lam = lamp[0];
    const size_t E = (size_t)BB * NH * TT * DVV;
    const ushort* o1p = (const ushort*)Obuf + (size_t)rid * DVV + lane * 4;
    const ushort4 u1 = *reinterpret_cast<const ushort4*>(o1p);
    const ushort4 u2 = *reinterpret_cast<const ushort4*>(o1p + E);
    float val[4];
    val[0] = bfu2f(u1.x) - lam * bfu2f(u2.x);
    val[1] = bfu2f(u1.y) - lam * bfu2f(u2.y);
    val[2] = bfu2f(u1.z) - lam * bfu2f(u2.z);
    val[3] = bfu2f(u1.w) - lam * bfu2f(u2.w);
    float sum = val[0] + val[1] + val[2] + val[3];
    float ss = val[0] * val[0] + val[1] * val[1] + val[2] * val[2] + val[3] * val[3];
#pragma unroll
    for (int mm = 1; mm < 64; mm <<= 1) {
        sum += __shfl_xor(sum, mm, 64);
        ss += __shfl_xor(ss, mm, 64);
    }
    const float mean = sum * (1.0f / 256.0f);
    const float var = ss * (1.0f / 256.0f) - mean * mean;
    const float rs = rsqrtf(var + 1e-5f);
    const int c = h * 256 + lane * 4;
    const float4 gwv = *reinterpret_cast<const float4*>(gw + c);
    const float4 gbv = *reinterpret_cast<const float4*>(gb + c);
    union { ushort4 u; short s[4]; } o;
    o.s[0] = f2bf_s(((val[0] - mean) * rs * gwv.x + gbv.x) * ONE_MINUS_LI);
    o.s[1] = f2bf_s(((val[1] - mean) * rs * gwv.y + gbv.y) * ONE_MINUS_LI);
    o.s[2] = f2bf_s(((val[2] - mean) * rs * gwv.z + gbv.z) * ONE_MINUS_LI);
    o.s[3] = f2bf_s(((val[3] - mean) * rs * gwv.w + gbv.w) * ONE_MINUS_LI);
    const int bt = b * TT + t;
    *reinterpret_cast<ushort4*>((ushort*)obf + (size_t)bt * 4096 + c) = o.u;
}

// ---------------- launch ----------------
extern "C" void kernel_launch(void* const* d_in, const int* in_sizes, int n_in,
                              void* d_out, int out_size, void* d_ws, size_t ws_size,
                              hipStream_t stream) {
    const float* x = (const float*)d_in[0];
    const float* Wq = (const float*)d_in[1];
    const float* Wk = (const float*)d_in[2];
    const float* Wv = (const float*)d_in[3];
    const float* Wo = (const float*)d_in[4];
    const float* lq1 = (const float*)d_in[5];
    const float* lk1 = (const float*)d_in[6];
    const float* lq2 = (const float*)d_in[7];
    const float* lk2 = (const float*)d_in[8];
    const float* gw = (const float*)d_in[9];
    const float* gb = (const float*)d_in[10];
    const int* pos = (const int*)d_in[11];

    char* ws = (char*)d_ws;
    const size_t oXB = 0;                   // x bf16               8,388,608
    const size_t oWQKV = 8388608;           // [Wq;Wk;Wv] bf16     25,165,824
    const size_t oWO = 33554432;            // Wo bf16             16,777,216
    const size_t oQKVF = 50331648;          // QKV f32 [2048][6144] 50,331,648
    const size_t oOB = 50331648;            // attn out bf16 (alias, 33,554,432)
    const size_t oLAM = 83886080;           // lambda f32 (in dead QKVF tail)
    const size_t oQB = 100663296;           // q rope bf16         16,777,216
    const size_t oKB = 117440512;           // k rope bf16          4,194,304
    const size_t oVT = 121634816;           // v^T bf16             4,194,304
    const size_t oON = 125829120;           // post-GN bf16        16,777,216  (end 142,606,336)

    auto bfp = [&](size_t off) { return (__hip_bfloat16*)(ws + off); };
    auto fp = [&](size_t off) { return (float*)(ws + off); };

    int n;
    n = BB * TT * DD / 4;
    cast_bf16<<<dim3((n + 255) / 256), 256, 0, stream>>>(x, bfp(oXB), n);
    n = 4096 * 2048 / 4;
    cast_bf16<<<dim3((n + 255) / 256), 256, 0, stream>>>(Wq, bfp(oWQKV), n);
    n = 1024 * 2048 / 4;
    cast_bf16<<<dim3((n + 255) / 256), 256, 0, stream>>>(Wk, bfp(oWQKV + (size_t)4096 * 2048 * 2), n);
    cast_bf16<<<dim3((n + 255) / 256), 256, 0, stream>>>(Wv, bfp(oWQKV + (size_t)5120 * 2048 * 2), n);
    n = 2048 * 4096 / 4;
    cast_bf16<<<dim3((n + 255) / 256), 256, 0, stream>>>(Wo, bfp(oWO), n);

    // fused QKV projection: [2048][2048] x [6144][2048]^T -> [2048][6144]
    gemm128<<<dim3(6144 / 128, 2048 / 128), 256, 0, stream>>>(bfp(oXB), bfp(oWQKV), fp(oQKVF), 2048, 6144, 2048);

    // rope + reorg (Q gets QK_SCALE*log2e folded in)
    n = BB * TT * NH * 2 * 64;
    rope_qk<<<dim3((n + 255) / 256), 256, 0, stream>>>(fp(oQKVF), 6144, 0, NH, 4, pos, bfp(oQB), QSCALE);
    n = BB * TT * NKV * 2 * 64;
    rope_qk<<<dim3((n + 255) / 256), 256, 0, stream>>>(fp(oQKVF), 6144, 4096, NKV, 2, pos, bfp(oKB), 1.0f);
    n = BB * NKV * DVV * TT;
    vtrans<<<dim3((n + 255) / 256), 256, 0, stream>>>(fp(oQKVF), bfp(oVT));

    lam_k<<<dim3(1), 64, 0, stream>>>(lq1, lk1, lq2, lk2, fp(oLAM));

    // attention (both variants)
    attn_fused<<<dim3(TT / 64, BB * NH, 2), 256, 0, stream>>>(bfp(oQB), bfp(oKB), bfp(oVT), bfp(oOB));

    // combine + groupnorm
    gn_combine<<<dim3(BB * NH * TT / 4), 256, 0, stream>>>(bfp(oOB), fp(oLAM), gw, gb, bfp(oON));

    // output projection
    gemm128<<<dim3(2048 / 128, 2048 / 128), 256, 0, stream>>>(bfp(oON), bfp(oWO), (float*)d_out, 2048, 2048, 4096);
}

// Round 4
// 438.263 us; speedup vs baseline: 1.7882x; 1.1052x over previous
//
#include <hip/hip_runtime.h>
#include <hip/hip_bf16.h>

#define BB 2
#define TT 1024
#define DD 2048
#define NH 16
#define NKV 4
#define DHD 128
#define DVV 256

#define LAMBDA_INIT 0.35550906759096927f
#define ONE_MINUS_LI 0.6444909324090307f
// QK scale * log2(e), folded into Q at rope time (softmax runs in exp2 domain)
#define QSCALE (0.08838834764831845f * 1.4426950408889634f)

typedef __attribute__((ext_vector_type(8))) short bf16x8;
typedef __attribute__((ext_vector_type(4))) float f32x4;

static __device__ __forceinline__ short f2bf_s(float x) {
    __hip_bfloat16 h = __float2bfloat16(x);
    return __builtin_bit_cast(short, h);
}
static __device__ __forceinline__ float bfu2f(unsigned short u) {
    union { float f; unsigned int u32; } x;
    x.u32 = ((unsigned int)u) << 16;
    return x.f;
}

#define GLOAD_LDS16(g, l)                                                      \
    __builtin_amdgcn_global_load_lds(                                          \
        (const __attribute__((address_space(1))) unsigned int*)(g),            \
        (__attribute__((address_space(3))) unsigned int*)(l), 16, 0, 0)

// ---------------- f32 -> bf16 cast (vectorized x4) ----------------
__global__ void cast_bf16(const float* __restrict__ in, __hip_bfloat16* __restrict__ out, int n4) {
    int i = blockIdx.x * blockDim.x + threadIdx.x;
    if (i >= n4) return;
    const float4 v = reinterpret_cast<const float4*>(in)[i];
    union { ushort4 u; __hip_bfloat16 b[4]; } o;
    o.b[0] = __float2bfloat16(v.x);
    o.b[1] = __float2bfloat16(v.y);
    o.b[2] = __float2bfloat16(v.z);
    o.b[3] = __float2bfloat16(v.w);
    reinterpret_cast<ushort4*>(out)[i] = o.u;
}

// ---------------- NT GEMM, 2-phase double-buffered (T3 minimum recipe) ----------------
// C[z][M][N] = A[:, z*kLen : (z+1)*kLen] * B[:, same]^T   (bf16 in, f32 out)
// 128x128 tile, BK=32, 4 waves; one barrier + prefetch-overlap per K-step.
// Row stride of A/B is sK elements; blockIdx.z selects the K-split.
__global__ __launch_bounds__(256) void gemm128_db(const __hip_bfloat16* __restrict__ A,
                                                  const __hip_bfloat16* __restrict__ Bm,
                                                  float* __restrict__ C,
                                                  int M, int N, int sK, int kLen) {
    __shared__ ushort As[2][128 * 32];
    __shared__ ushort Bs[2][128 * 32];
    const int tid = threadIdx.x;
    const int lane = tid & 63, wid = tid >> 6;
    const int lo = lane & 15, hi = lane >> 4;
    const int wr = wid >> 1, wc = wid & 1;
    const int m0 = blockIdx.y * 128, n0 = blockIdx.x * 128;
    const int kOff = blockIdx.z * kLen;

    const ushort* gA = (const ushort*)A;
    const ushort* gB = (const ushort*)Bm;
    C += (size_t)blockIdx.z * M * N;

    // staging geometry: 512 x 16B chunks per matrix, 2 per thread
    const int c0row = tid >> 2;            // idx = q*256+tid -> row = idx>>2
    const int c0col = (tid & 3) << 3;      // ushort col

    auto STAGE = [&](int buf, int kg) {
#pragma unroll
        for (int q = 0; q < 2; ++q) {
            const int row = q * 64 + c0row;
            const int idx = q * 256 + tid;
            GLOAD_LDS16(gA + (size_t)(m0 + row) * sK + kg + c0col, &As[buf][idx << 3]);
            GLOAD_LDS16(gB + (size_t)(n0 + row) * sK + kg + c0col, &Bs[buf][idx << 3]);
        }
    };

    f32x4 acc[4][4];
#pragma unroll
    for (int mi = 0; mi < 4; ++mi)
#pragma unroll
        for (int ni = 0; ni < 4; ++ni) acc[mi][ni] = (f32x4){0.f, 0.f, 0.f, 0.f};

    STAGE(0, kOff);
    const int nt = kLen >> 5;
    for (int t = 0; t < nt; ++t) {
        __syncthreads();  // drains stage into buf[t&1]; all waves done reading buf[(t-1)&1]
        if (t + 1 < nt) STAGE((t + 1) & 1, kOff + ((t + 1) << 5));
        const ushort* as = &As[t & 1][0];
        const ushort* bs = &Bs[t & 1][0];
        bf16x8 af[4], bfr[4];
#pragma unroll
        for (int mi = 0; mi < 4; ++mi)
            af[mi] = *reinterpret_cast<const bf16x8*>(&as[(wr * 64 + mi * 16 + lo) * 32 + hi * 8]);
#pragma unroll
        for (int ni = 0; ni < 4; ++ni)
            bfr[ni] = *reinterpret_cast<const bf16x8*>(&bs[(wc * 64 + ni * 16 + lo) * 32 + hi * 8]);
#pragma unroll
        for (int mi = 0; mi < 4; ++mi)
#pragma unroll
            for (int ni = 0; ni < 4; ++ni)
                acc[mi][ni] = __builtin_amdgcn_mfma_f32_16x16x32_bf16(af[mi], bfr[ni], acc[mi][ni], 0, 0, 0);
    }
#pragma unroll
    for (int mi = 0; mi < 4; ++mi)
#pragma unroll
        for (int ni = 0; ni < 4; ++ni)
#pragma unroll
            for (int r = 0; r < 4; ++r)
                C[(size_t)(m0 + wr * 64 + mi * 16 + hi * 4 + r) * N + (n0 + wc * 64 + ni * 16 + lo)] =
                    acc[mi][ni][r];
}

// ---------------- split-K reduce: out = p[0] + p[1] (float4) ----------------
__global__ void addf4(const float* __restrict__ p, float* __restrict__ out, int n4) {
    int i = blockIdx.x * blockDim.x + threadIdx.x;
    if (i >= n4) return;
    const float4 a = reinterpret_cast<const float4*>(p)[i];
    const float4 b = reinterpret_cast<const float4*>(p)[i + n4];
    float4 o;
    o.x = a.x + b.x; o.y = a.y + b.y; o.z = a.z + b.z; o.w = a.w + b.w;
    reinterpret_cast<float4*>(out)[i] = o;
}

// ---------------- RoPE + reorg (reads fused QKV f32, writes [e][b][head][t][128] bf16) ----
__global__ void rope_qk(const float* __restrict__ in, int stride, int col_base, int nheads, int hshift,
                        const int* __restrict__ pos, __hip_bfloat16* __restrict__ out, float scale) {
    int idx = blockIdx.x * blockDim.x + threadIdx.x;
    int total = BB * TT * nheads * 2 * 64;
    if (idx >= total) return;
    int d2 = idx & 63;
    int rest = idx >> 6;
    int e = rest & 1;
    int rest2 = rest >> 1;
    int head = rest2 & (nheads - 1);
    int bt = rest2 >> hshift;
    int t = bt & (TT - 1);
    int b = bt >> 10;

    const float* src = in + (size_t)bt * stride + col_base + head * 256 + e * 128 + 2 * d2;
    float x1 = src[0], x2 = src[1];
    float inv = expf(-(float)d2 * (2.0f / 128.0f) * 9.210340371976184f);
    float fr = (float)pos[t] * inv;
    float sn, cs;
    sincosf(fr, &sn, &cs);
    float o1 = (x1 * cs - x2 * sn) * scale;
    float o2 = (x1 * sn + x2 * cs) * scale;
    __hip_bfloat16* dst = out + ((((size_t)e * BB + b) * nheads + head) * TT + t) * DHD + 2 * d2;
    dst[0] = __float2bfloat16(o1);
    dst[1] = __float2bfloat16(o2);
}

// ---------------- V transpose via LDS tile: QKV f32 -> [b][kv][dv][t] bf16 ----------------
// 64(t) x 64(dv) tiles; coalesced global reads and writes; padded LDS (65) kills conflicts.
__global__ __launch_bounds__(256) void vtrans(const float* __restrict__ in, __hip_bfloat16* __restrict__ out) {
    __shared__ float tle[64][65];
    const int t0 = blockIdx.x * 64;
    const int z = blockIdx.y;            // b*16 + kv*4 + dvblk
    const int dv0 = (z & 3) * 64;
    const int kvi = (z >> 2) & 3;
    const int b = z >> 4;
    const int tid = threadIdx.x;
    const int rt = tid >> 6, ct = tid & 63;
#pragma unroll
    for (int p = 0; p < 16; ++p) {
        const int ti = p * 4 + rt;
        tle[ti][ct] = in[(size_t)(b * TT + t0 + ti) * 6144 + 5120 + kvi * 256 + dv0 + ct];
    }
    __syncthreads();
#pragma unroll
    for (int p = 0; p < 16; ++p) {
        const int dv = p * 4 + rt;
        out[((size_t)(b * NKV + kvi) * DVV + dv0 + dv) * TT + t0 + ct] = __float2bfloat16(tle[ct][dv]);
    }
}

// ---------------- lambda scalar ----------------
__global__ void lam_k(const float* __restrict__ lq1, const float* __restrict__ lk1,
                      const float* __restrict__ lq2, const float* __restrict__ lk2,
                      float* __restrict__ lam) {
    int l = threadIdx.x;  // 64
    float s1 = lq1[l] * lk1[l] + lq1[l + 64] * lk1[l + 64];
    float s2 = lq2[l] * lk2[l] + lq2[l + 64] * lk2[l + 64];
#pragma unroll
    for (int mm = 1; mm < 64; mm <<= 1) {
        s1 += __shfl_xor(s1, mm, 64);
        s2 += __shfl_xor(s2, mm, 64);
    }
    if (l == 0) lam[0] = expf(s1) - expf(s2) + LAMBDA_INIT;
}

// ---------------- flash attention v3 (unchanged from round 3, passing) ----------------
__global__ __launch_bounds__(256) void attn_fused(const __hip_bfloat16* __restrict__ qb,
                                                  const __hip_bfloat16* __restrict__ kb,
                                                  const __hip_bfloat16* __restrict__ vtb,
                                                  __hip_bfloat16* __restrict__ Obuf) {
    const int tid = threadIdx.x;
    const int wid = tid >> 6;
    const int lane = tid & 63;
    const int lo = lane & 15, hi = lane >> 4;
    const int qt = (int)gridDim.x - 1 - blockIdx.x;  // LPT: heavy blocks first
    const int bh = blockIdx.y;
    const int e = blockIdx.z;
    const int b = bh >> 4, h = bh & 15;
    const int kv = h >> 2;

    const ushort* qp = (const ushort*)qb + (((size_t)e * BB + b) * NH + h) * (size_t)TT * DHD;
    const ushort* kp = (const ushort*)kb + (((size_t)e * BB + b) * NKV + kv) * (size_t)TT * DHD;
    const ushort* vp = (const ushort*)vtb + ((size_t)b * NKV + kv) * (size_t)DVV * TT;

    const int q0 = qt * 64 + wid * 16;

    __shared__ ushort Ks[64 * 128];   // 16 KB
    __shared__ ushort Vs[256 * 64];   // 32 KB

    bf16x8 qf[4];
#pragma unroll
    for (int kk = 0; kk < 4; ++kk)
        qf[kk] = *reinterpret_cast<const bf16x8*>(qp + (size_t)(q0 + lo) * DHD + kk * 32 + hi * 8);

    f32x4 O[16];
#pragma unroll
    for (int nc = 0; nc < 16; ++nc) O[nc] = (f32x4){0.f, 0.f, 0.f, 0.f};
    float m = -3e38f, l = 0.f;   // per-lane: q-row = q0 + lo (replicated over hi)

    const int nkt = qt + 1;
    for (int kt = 0; kt < nkt; ++kt) {
        const int kbase = kt * 64;
#pragma unroll
        for (int p2 = 0; p2 < 4; ++p2) {
            const int idx = p2 * 256 + tid;
            const int row = idx >> 4, c = idx & 15;
            const int cp = c ^ ((row & 3) | ((row >> 1) & 4));
            GLOAD_LDS16(kp + (((size_t)(kbase + row)) << 7) + (cp << 3), &Ks[idx << 3]);
        }
#pragma unroll
        for (int p2 = 0; p2 < 8; ++p2) {
            const int idx = p2 * 256 + tid;
            const int dv = idx >> 3, c = idx & 7;
            const int cp = c ^ (dv & 7);
            GLOAD_LDS16(vp + (size_t)dv * TT + kbase + (cp << 3), &Vs[idx << 3]);
        }
        __syncthreads();

        f32x4 s[4];
#pragma unroll
        for (int n = 0; n < 4; ++n) s[n] = (f32x4){0.f, 0.f, 0.f, 0.f};
        __builtin_amdgcn_s_setprio(1);
#pragma unroll
        for (int n = 0; n < 4; ++n) {
            const int R = ((n >> 1) << 5) + ((lo >> 2) << 3) + ((n & 1) << 2) + (lo & 3);
            const int swz = ((R & 3) | ((R >> 1) & 4)) << 4;
#pragma unroll
            for (int kk = 0; kk < 4; ++kk) {
                bf16x8 kf = *reinterpret_cast<const bf16x8*>(
                    (const char*)Ks + R * 256 + ((kk * 64 + hi * 16) ^ swz));
                s[n] = __builtin_amdgcn_mfma_f32_16x16x32_bf16(kf, qf[kk], s[n], 0, 0, 0);
            }
        }
        __builtin_amdgcn_s_setprio(0);

        if (kt == nkt - 1) {
#pragma unroll
            for (int n = 0; n < 4; ++n) {
                const int kb0 = kbase + ((n >> 1) << 5) + ((n & 1) << 2) + hi * 8;
#pragma unroll
                for (int r = 0; r < 4; ++r)
                    if (kb0 + r > q0 + lo) s[n][r] = -3e38f;
            }
        }
        float tm = s[0][0];
#pragma unroll
        for (int n = 0; n < 4; ++n)
#pragma unroll
            for (int r = 0; r < 4; ++r) tm = fmaxf(tm, s[n][r]);
        tm = fmaxf(tm, __shfl_xor(tm, 16, 64));
        tm = fmaxf(tm, __shfl_xor(tm, 32, 64));
        if (!__all(tm <= m + 11.f)) {
            const float mn = fmaxf(m, tm);
            const float resc = __builtin_amdgcn_exp2f(m - mn);
            m = mn;
            l *= resc;
            float ro[4];
#pragma unroll
            for (int r = 0; r < 4; ++r) ro[r] = __shfl(resc, hi * 4 + r, 64);
#pragma unroll
            for (int nc = 0; nc < 16; ++nc)
#pragma unroll
                for (int r = 0; r < 4; ++r) O[nc][r] *= ro[r];
        }
        float rs = 0.f;
#pragma unroll
        for (int n = 0; n < 4; ++n)
#pragma unroll
            for (int r = 0; r < 4; ++r) {
                const float p = __builtin_amdgcn_exp2f(s[n][r] - m);
                s[n][r] = p;
                rs += p;
            }
        rs += __shfl_xor(rs, 16, 64);
        rs += __shfl_xor(rs, 32, 64);
        l += rs;
        bf16x8 pf[2];
#pragma unroll
        for (int n = 0; n < 4; ++n)
#pragma unroll
            for (int r = 0; r < 4; ++r) pf[n >> 1][(n & 1) * 4 + r] = f2bf_s(s[n][r]);
        __builtin_amdgcn_s_setprio(1);
#pragma unroll
        for (int nc = 0; nc < 16; ++nc) {
            const int vrow = (nc * 16 + lo) * 128;
            const int vswz = (lo & 7) << 4;
#pragma unroll
            for (int ks = 0; ks < 2; ++ks) {
                bf16x8 vf = *reinterpret_cast<const bf16x8*>(
                    (const char*)Vs + vrow + ((ks * 64 + hi * 16) ^ vswz));
                O[nc] = __builtin_amdgcn_mfma_f32_16x16x32_bf16(pf[ks], vf, O[nc], 0, 0, 0);
            }
        }
        __builtin_amdgcn_s_setprio(0);
        __syncthreads();
    }
    const float invl = 1.0f / l;
    float io[4];
#pragma unroll
    for (int r = 0; r < 4; ++r) io[r] = __shfl(invl, hi * 4 + r, 64);
    ushort* op = (ushort*)Obuf + (((size_t)e * BB + b) * NH + h) * (size_t)TT * DVV;
#pragma unroll
    for (int nc = 0; nc < 16; ++nc)
#pragma unroll
        for (int r = 0; r < 4; ++r)
            op[(size_t)(q0 + hi * 4 + r) * DVV + nc * 16 + lo] = (ushort)f2bf_s(O[nc][r] * io[r]);
}

// ---------------- combine + GroupNorm, one wave per (b,h,t) row ----------------
__global__ __launch_bounds__(256) void gn_combine(const __hip_bfloat16* __restrict__ Obuf,
                                                  const float* __restrict__ lamp,
                                                  const float* __restrict__ gw, const float* __restrict__ gb,
                                                  __hip_bfloat16* __restrict__ obf) {
    const int wid = threadIdx.x >> 6, lane = threadIdx.x & 63;
    const int rid = blockIdx.x * 4 + wid;  // (b*NH + h)*TT + t
    const int t = rid & (TT - 1);
    const int h = (rid >> 10) & 15;
    const int b = rid >> 14;
    const float lam = lamp[0];
    const size_t E = (size_t)BB * NH * TT * DVV;
    const ushort* o1p = (const ushort*)Obuf + (size_t)rid * DVV + lane * 4;
    const ushort4 u1 = *reinterpret_cast<const ushort4*>(o1p);
    const ushort4 u2 = *reinterpret_cast<const ushort4*>(o1p + E);
    float val[4];
    val[0] = bfu2f(u1.x) - lam * bfu2f(u2.x);
    val[1] = bfu2f(u1.y) - lam * bfu2f(u2.y);
    val[2] = bfu2f(u1.z) - lam * bfu2f(u2.z);
    val[3] = bfu2f(u1.w) - lam * bfu2f(u2.w);
    float sum = val[0] + val[1] + val[2] + val[3];
    float ss = val[0] * val[0] + val[1] * val[1] + val[2] * val[2] + val[3] * val[3];
#pragma unroll
    for (int mm = 1; mm < 64; mm <<= 1) {
        sum += __shfl_xor(sum, mm, 64);
        ss += __shfl_xor(ss, mm, 64);
    }
    const float mean = sum * (1.0f / 256.0f);
    const float var = ss * (1.0f / 256.0f) - mean * mean;
    const float rs = rsqrtf(var + 1e-5f);
    const int c = h * 256 + lane * 4;
    const float4 gwv = *reinterpret_cast<const float4*>(gw + c);
    const float4 gbv = *reinterpret_cast<const float4*>(gb + c);
    union { ushort4 u; short s[4]; } o;
    o.s[0] = f2bf_s(((val[0] - mean) * rs * gwv.x + gbv.x) * ONE_MINUS_LI);
    o.s[1] = f2bf_s(((val[1] - mean) * rs * gwv.y + gbv.y) * ONE_MINUS_LI);
    o.s[2] = f2bf_s(((val[2] - mean) * rs * gwv.z + gbv.z) * ONE_MINUS_LI);
    o.s[3] = f2bf_s(((val[3] - mean) * rs * gwv.w + gbv.w) * ONE_MINUS_LI);
    const int bt = b * TT + t;
    *reinterpret_cast<ushort4*>((ushort*)obf + (size_t)bt * 4096 + c) = o.u;
}

// ---------------- launch ----------------
extern "C" void kernel_launch(void* const* d_in, const int* in_sizes, int n_in,
                              void* d_out, int out_size, void* d_ws, size_t ws_size,
                              hipStream_t stream) {
    const float* x = (const float*)d_in[0];
    const float* Wq = (const float*)d_in[1];
    const float* Wk = (const float*)d_in[2];
    const float* Wv = (const float*)d_in[3];
    const float* Wo = (const float*)d_in[4];
    const float* lq1 = (const float*)d_in[5];
    const float* lk1 = (const float*)d_in[6];
    const float* lq2 = (const float*)d_in[7];
    const float* lk2 = (const float*)d_in[8];
    const float* gw = (const float*)d_in[9];
    const float* gb = (const float*)d_in[10];
    const int* pos = (const int*)d_in[11];

    char* ws = (char*)d_ws;
    const size_t oXB = 0;                   // x bf16               8,388,608
    const size_t oWQKV = 8388608;           // [Wq;Wk;Wv] bf16     25,165,824
    const size_t oWO = 33554432;            // Wo bf16             16,777,216
    const size_t oQKVF = 50331648;          // QKV f32 [2048][6144] 50,331,648
    const size_t oOB = 50331648;            // attn out bf16 (alias, 33,554,432)
    const size_t oPK = 50331648;            // split-K partials f32 (alias, 33,554,432)
    const size_t oLAM = 83886080;           // lambda f32 (in dead QKVF tail)
    const size_t oQB = 100663296;           // q rope bf16         16,777,216
    const size_t oKB = 117440512;           // k rope bf16          4,194,304
    const size_t oVT = 121634816;           // v^T bf16             4,194,304
    const size_t oON = 125829120;           // post-GN bf16        16,777,216  (end 142,606,336)

    auto bfp = [&](size_t off) { return (__hip_bfloat16*)(ws + off); };
    auto fp = [&](size_t off) { return (float*)(ws + off); };

    int n;
    n = BB * TT * DD / 4;
    cast_bf16<<<dim3((n + 255) / 256), 256, 0, stream>>>(x, bfp(oXB), n);
    n = 4096 * 2048 / 4;
    cast_bf16<<<dim3((n + 255) / 256), 256, 0, stream>>>(Wq, bfp(oWQKV), n);
    n = 1024 * 2048 / 4;
    cast_bf16<<<dim3((n + 255) / 256), 256, 0, stream>>>(Wk, bfp(oWQKV + (size_t)4096 * 2048 * 2), n);
    cast_bf16<<<dim3((n + 255) / 256), 256, 0, stream>>>(Wv, bfp(oWQKV + (size_t)5120 * 2048 * 2), n);
    n = 2048 * 4096 / 4;
    cast_bf16<<<dim3((n + 255) / 256), 256, 0, stream>>>(Wo, bfp(oWO), n);

    // fused QKV projection: [2048][2048] x [6144][2048]^T -> [2048][6144]
    gemm128_db<<<dim3(6144 / 128, 2048 / 128, 1), 256, 0, stream>>>(
        bfp(oXB), bfp(oWQKV), fp(oQKVF), 2048, 6144, 2048, 2048);

    // rope + reorg (Q gets QK_SCALE*log2e folded in)
    n = BB * TT * NH * 2 * 64;
    rope_qk<<<dim3((n + 255) / 256), 256, 0, stream>>>(fp(oQKVF), 6144, 0, NH, 4, pos, bfp(oQB), QSCALE);
    n = BB * TT * NKV * 2 * 64;
    rope_qk<<<dim3((n + 255) / 256), 256, 0, stream>>>(fp(oQKVF), 6144, 4096, NKV, 2, pos, bfp(oKB), 1.0f);
    vtrans<<<dim3(TT / 64, BB * NKV * 4), 256, 0, stream>>>(fp(oQKVF), bfp(oVT));

    lam_k<<<dim3(1), 64, 0, stream>>>(lq1, lk1, lq2, lk2, fp(oLAM));

    // attention (both variants)
    attn_fused<<<dim3(TT / 64, BB * NH, 2), 256, 0, stream>>>(bfp(oQB), bfp(oKB), bfp(oVT), bfp(oOB));

    // combine + groupnorm
    gn_combine<<<dim3(BB * NH * TT / 4), 256, 0, stream>>>(bfp(oOB), fp(oLAM), gw, gb, bfp(oON));

    // output projection, split-K x2 in one dispatch (512 blocks), then reduce
    gemm128_db<<<dim3(2048 / 128, 2048 / 128, 2), 256, 0, stream>>>(
        bfp(oON), bfp(oWO), fp(oPK), 2048, 2048, 4096, 2048);
    n = 2048 * 2048 / 4;
    addf4<<<dim3((n + 255) / 256), 256, 0, stream>>>(fp(oPK), (float*)d_out, n);
}